// Round 6
// baseline (668.786 us; speedup 1.0000x reference)
//
#include <hip/hip_runtime.h>
#include <hip/hip_bf16.h>
#include <cmath>

typedef __hip_bfloat16 bf16;
typedef __bf16 bf16x8 __attribute__((ext_vector_type(8)));
typedef float floatx4 __attribute__((ext_vector_type(4)));

__device__ inline floatx4 mfma16(bf16x8 a, bf16x8 b, floatx4 c) {
  return __builtin_amdgcn_mfma_f32_16x16x32_bf16(a, b, c, 0, 0, 0);
}

// async global->LDS, 16B/lane; lds dest must be wave-uniform (HW adds lane*16)
__device__ inline void async_ld16(const void* g, void* l) {
  __builtin_amdgcn_global_load_lds((const __attribute__((address_space(1))) void*)g,
                                   (__attribute__((address_space(3))) void*)l,
                                   16, 0, 0);
}

// pack 8 fp32 -> 8 bf16 (RNE) -> one 16B store
__device__ inline uint4 pack8(float4 a, float4 b) {
  union { uint4 u; bf16 h[8]; } t;
  t.h[0] = __float2bfloat16(a.x); t.h[1] = __float2bfloat16(a.y);
  t.h[2] = __float2bfloat16(a.z); t.h[3] = __float2bfloat16(a.w);
  t.h[4] = __float2bfloat16(b.x); t.h[5] = __float2bfloat16(b.y);
  t.h[6] = __float2bfloat16(b.z); t.h[7] = __float2bfloat16(b.w);
  return t.u;
}

// bulk fp32 -> bf16 convert, 8 elems/thread
__global__ __launch_bounds__(256)
void cvt_f32_bf16(const float* __restrict__ s, bf16* __restrict__ d, int n8) {
  const int i = blockIdx.x * 256 + threadIdx.x;
  if (i >= n8) return;
  const float4 a = ((const float4*)s)[2 * i];
  const float4 b = ((const float4*)s)[2 * i + 1];
  ((uint4*)d)[i] = pack8(a, b);
}

// ball[5120] = concat(bq[4096], bk[512], bv[512])
__global__ void concat_bias3(const float* __restrict__ q, const float* __restrict__ k,
                             const float* __restrict__ v, float* __restrict__ o) {
  const int i = blockIdx.x * 256 + threadIdx.x;  // 5120 threads
  if (i < 4096) o[i] = q[i];
  else if (i < 4608) o[i] = k[i - 4096];
  else o[i] = v[i - 4608];
}

// Q pre-scale: 1/sqrt(64) * log2(e)  -> softmax runs in exp2 domain
#define QSCALE 0.1803368801111601f

// C = A[M,K] @ B[N,K]^T + bias[N]; bf16 MFMA, fp32 accumulate.
// A_BF/B_BF: operand dtype (bf16 -> global_load_lds path; fp32 -> cvt staging).
// OUT_MODE: 0 = bf16 [M][N] (xval scaled by qmul); 1 = fp32 [M][N];
//           2 = bf16 transposed Ct[col*M+row];
//           4 = fused QKV route: col<4096 -> Cp (Q, scaled by qmul),
//               col<4608 -> Cq (K), else -> Ct (V transposed)
template <int A_BF, int B_BF, int OUT_MODE>
__global__ __launch_bounds__(256)
void gemm_bt_bias(const void* __restrict__ Ap, const void* __restrict__ Bp,
                  const float* __restrict__ bias, void* __restrict__ Cp,
                  void* __restrict__ Cqp, void* __restrict__ Ctp,
                  int M, int N, int K, float qmul) {
  __shared__ __align__(16) bf16 sA[128 * 32];
  __shared__ __align__(16) bf16 sB[128 * 32];
  const int tid  = threadIdx.x;
  const int wave = tid >> 6;
  const int lane = tid & 63;
  const int quad = lane >> 4;
  const int l15  = lane & 15;
  const int bm = blockIdx.y * 128;
  const int bn = blockIdx.x * 128;
  const int wm = (wave & 1) * 64;
  const int wn = (wave >> 1) * 64;

  floatx4 acc[4][4] = {};

  const int g0 = tid, g1 = tid + 256;
  const int arow0 = bm + (g0 >> 2), acol0 = (g0 & 3) * 8;
  const int arow1 = bm + (g1 >> 2), acol1 = (g1 & 3) * 8;
  int brow0 = bn + (g0 >> 2); if (brow0 >= N) brow0 = N - 1;  // N edge: clamp (stores guarded)
  int brow1 = bn + (g1 >> 2); if (brow1 >= N) brow1 = N - 1;

  for (int k0 = 0; k0 < K; k0 += 32) {
    __syncthreads();  // prev iteration's ds_reads done before overwrite
    if (A_BF) {
      const bf16* A = (const bf16*)Ap;
      async_ld16(A + (size_t)arow0 * K + k0 + acol0, sA + wave * 512);
      async_ld16(A + (size_t)arow1 * K + k0 + acol1, sA + 2048 + wave * 512);
    } else {
      const float* A = (const float*)Ap;
      const float* p0 = A + (size_t)arow0 * K + k0 + acol0;
      const float* p1 = A + (size_t)arow1 * K + k0 + acol1;
      *(uint4*)(sA + tid * 8)        = pack8(*(const float4*)p0, *(const float4*)(p0 + 4));
      *(uint4*)(sA + 2048 + tid * 8) = pack8(*(const float4*)p1, *(const float4*)(p1 + 4));
    }
    if (B_BF) {
      const bf16* B = (const bf16*)Bp;
      async_ld16(B + (size_t)brow0 * K + k0 + acol0, sB + wave * 512);
      async_ld16(B + (size_t)brow1 * K + k0 + acol1, sB + 2048 + wave * 512);
    } else {
      const float* B = (const float*)Bp;
      const float* p0 = B + (size_t)brow0 * K + k0 + acol0;
      const float* p1 = B + (size_t)brow1 * K + k0 + acol1;
      *(uint4*)(sB + tid * 8)        = pack8(*(const float4*)p0, *(const float4*)(p0 + 4));
      *(uint4*)(sB + 2048 + tid * 8) = pack8(*(const float4*)p1, *(const float4*)(p1 + 4));
    }
    __syncthreads();  // drains lds-DMA (vmcnt) + ds_writes (lgkmcnt)

    bf16x8 aF[4], bF[4];
#pragma unroll
    for (int mi = 0; mi < 4; ++mi)
      aF[mi] = *(const bf16x8*)(sA + (wm + mi * 16 + l15) * 32 + quad * 8);
#pragma unroll
    for (int ni = 0; ni < 4; ++ni)
      bF[ni] = *(const bf16x8*)(sB + (wn + ni * 16 + l15) * 32 + quad * 8);
#pragma unroll
    for (int mi = 0; mi < 4; ++mi)
#pragma unroll
      for (int ni = 0; ni < 4; ++ni)
        acc[mi][ni] = mfma16(aF[mi], bF[ni], acc[mi][ni]);
  }

  // epilogue: C/D layout col=lane&15, row=quad*4+reg (m89-verified)
#pragma unroll
  for (int ni = 0; ni < 4; ++ni) {
    const int col = bn + wn + ni * 16 + l15;
    if (col >= N) continue;
    const float bv = bias[col];
#pragma unroll
    for (int mi = 0; mi < 4; ++mi) {
      const int row = bm + wm + mi * 16 + quad * 4;
#pragma unroll
      for (int r = 0; r < 4; ++r) {
        const float val = acc[mi][ni][r] + bv;
        if (OUT_MODE == 0) {
          ((bf16*)Cp)[(size_t)(row + r) * N + col] = __float2bfloat16(val * qmul);
        } else if (OUT_MODE == 1) {
          ((float*)Cp)[(size_t)(row + r) * N + col] = val;
        } else if (OUT_MODE == 2) {
          ((bf16*)Ctp)[(size_t)col * M + row + r] = __float2bfloat16(val);
        } else {  // fused QKV routing (segment uniform across the 16-lane store group)
          if (col < 4096)      ((bf16*)Cp)[(size_t)(row + r) * 4096 + col] = __float2bfloat16(val * qmul);
          else if (col < 4608) ((bf16*)Cqp)[(size_t)(row + r) * 512 + (col - 4096)] = __float2bfloat16(val);
          else                 ((bf16*)Ctp)[(size_t)(col - 4608) * M + row + r] = __float2bfloat16(val);
        }
      }
    }
  }
}

// Fused causal GQA attention, flash-style online softmax (exp2 domain; Q pre-scaled).
// grid: (qb, h). 4 waves; each wave owns 16 q-rows. LDS pitch 72 (conflict-free b128).
// K/V tiles register-prefetched one iteration ahead. LDS caps us at 4 blocks/CU =
// 4 waves/EU, so __launch_bounds__(256,4) raises the VGPR cap to 128 for free —
// without it the compiler targets 8 waves/EU (64 VGPR) and SPILLS the prefetch
// (round-5 counters: WRITE_SIZE 16->73 MB).
__global__ __launch_bounds__(256, 4)
void attn_fused(const bf16* __restrict__ Q, const bf16* __restrict__ Kc,
                const bf16* __restrict__ Vt, bf16* __restrict__ AO) {
  constexpr int HD = 4096, KD = 512, SEQ = 2048, AP = 72;
  constexpr float NEG = -1e30f;
  __shared__ __align__(16) bf16 sQ[64 * AP];
  __shared__ __align__(16) bf16 sK[64 * AP];   // [t][d]
  __shared__ __align__(16) bf16 sVt[64 * AP];  // [d][t]  (from global V^T)
  __shared__ __align__(16) bf16 sP[64 * AP];

  const int qb = (int)gridDim.x - 1 - blockIdx.x;  // heavy blocks dispatch first
  const int h  = blockIdx.y;
  const int kvh = h >> 3;        // h // G, G=8
  const int tid = threadIdx.x, wave = tid >> 6, lane = tid & 63;
  const int quad = lane >> 4, l15 = lane & 15;
  const int sq0 = qb * 64;

  // stage Q tile [64 q][64 d]
#pragma unroll
  for (int i = 0; i < 2; ++i) {
    const int g = tid + i * 256;
    const int r = g >> 3, c = (g & 7) * 8;
    *(uint4*)(sQ + r * AP + c) = *(const uint4*)(Q + (size_t)(sq0 + r) * HD + h * 64 + c);
  }

  // register prefetch of K/V tile 0
  int rr[2], cc[2];
  uint4 rk[2], rv[2];
#pragma unroll
  for (int i = 0; i < 2; ++i) {
    const int g = tid + i * 256;
    rr[i] = g >> 3; cc[i] = (g & 7) * 8;
    rk[i] = *(const uint4*)(Kc + (size_t)rr[i] * KD + kvh * 64 + cc[i]);
    rv[i] = *(const uint4*)(Vt + (size_t)(kvh * 64 + rr[i]) * SEQ + cc[i]);
  }

  floatx4 o_acc[4] = {};
  float m_run[4], l_run[4];
#pragma unroll
  for (int r = 0; r < 4; ++r) { m_run[r] = NEG; l_run[r] = 0.f; }

  for (int kt = 0; kt <= qb; ++kt) {   // analytic causality: skip fully-masked key tiles
    const int st0 = kt * 64;
    __syncthreads();                    // prior iteration's LDS reads complete (+ sQ iter0)
#pragma unroll
    for (int i = 0; i < 2; ++i) {
      *(uint4*)(sK + rr[i] * AP + cc[i])  = rk[i];
      *(uint4*)(sVt + rr[i] * AP + cc[i]) = rv[i];
    }
    __syncthreads();                    // tile kt visible

    if (kt < qb) {                      // issue tile kt+1 loads; consumed next iter
      const int st1 = st0 + 64;
#pragma unroll
      for (int i = 0; i < 2; ++i) {
        rk[i] = *(const uint4*)(Kc + (size_t)(st1 + rr[i]) * KD + kvh * 64 + cc[i]);
        rv[i] = *(const uint4*)(Vt + (size_t)(kvh * 64 + rr[i]) * SEQ + st1 + cc[i]);
      }
    }

    // S = Q K^T : 16 q-rows x 64 t-cols per wave (already in log2 units)
    floatx4 s_acc[4] = {};
#pragma unroll
    for (int ks = 0; ks < 2; ++ks) {
      const bf16x8 aF = *(const bf16x8*)(sQ + (wave * 16 + l15) * AP + ks * 32 + quad * 8);
#pragma unroll
      for (int ni = 0; ni < 4; ++ni) {
        const bf16x8 bF = *(const bf16x8*)(sK + (ni * 16 + l15) * AP + ks * 32 + quad * 8);
        s_acc[ni] = mfma16(aF, bF, s_acc[ni]);
      }
    }

    // online softmax (exp2); row = sq0+wave*16+quad*4+r, col = st0+ni*16+l15
    float x[4][4];
    float tmax[4] = {NEG, NEG, NEG, NEG};
    const int qrow = sq0 + wave * 16 + quad * 4;
#pragma unroll
    for (int ni = 0; ni < 4; ++ni) {
      const int tcol = st0 + ni * 16 + l15;
#pragma unroll
      for (int r = 0; r < 4; ++r) {
        float v = s_acc[ni][r];
        if (kt == qb && tcol > qrow + r) v = NEG;
        x[ni][r] = v;
        tmax[r] = fmaxf(tmax[r], v);
      }
    }
#pragma unroll
    for (int off = 1; off < 16; off <<= 1)
#pragma unroll
      for (int r = 0; r < 4; ++r)
        tmax[r] = fmaxf(tmax[r], __shfl_xor(tmax[r], off));

    float alpha[4], rsum[4];
#pragma unroll
    for (int r = 0; r < 4; ++r) {
      const float mn = fmaxf(m_run[r], tmax[r]);
      alpha[r] = exp2f(m_run[r] - mn);
      m_run[r] = mn;
      rsum[r] = 0.f;
    }
#pragma unroll
    for (int ni = 0; ni < 4; ++ni)
#pragma unroll
      for (int r = 0; r < 4; ++r) {
        const float p = exp2f(x[ni][r] - m_run[r]);
        x[ni][r] = p;
        rsum[r] += p;
      }
#pragma unroll
    for (int off = 1; off < 16; off <<= 1)
#pragma unroll
      for (int r = 0; r < 4; ++r)
        rsum[r] += __shfl_xor(rsum[r], off);
#pragma unroll
    for (int r = 0; r < 4; ++r)
      l_run[r] = l_run[r] * alpha[r] + rsum[r];
#pragma unroll
    for (int di = 0; di < 4; ++di)
#pragma unroll
      for (int r = 0; r < 4; ++r)
        o_acc[di][r] *= alpha[r];

    // P: C-layout -> LDS -> A-layout (wave-private rows; in-wave DS ordering)
#pragma unroll
    for (int ni = 0; ni < 4; ++ni)
#pragma unroll
      for (int r = 0; r < 4; ++r)
        sP[(wave * 16 + quad * 4 + r) * AP + ni * 16 + l15] = __float2bfloat16(x[ni][r]);

#pragma unroll
    for (int ks = 0; ks < 2; ++ks) {
      const bf16x8 aF = *(const bf16x8*)(sP + (wave * 16 + l15) * AP + ks * 32 + quad * 8);
#pragma unroll
      for (int di = 0; di < 4; ++di) {
        const bf16x8 bF = *(const bf16x8*)(sVt + (di * 16 + l15) * AP + ks * 32 + quad * 8);
        o_acc[di] = mfma16(aF, bF, o_acc[di]);
      }
    }
  }

  // normalize + store to AO[s][h*64+d]
#pragma unroll
  for (int di = 0; di < 4; ++di) {
    const int col = h * 64 + di * 16 + l15;
#pragma unroll
    for (int r = 0; r < 4; ++r) {
      const int row = sq0 + wave * 16 + quad * 4 + r;
      AO[(size_t)row * HD + col] = __float2bfloat16(o_acc[di][r] / l_run[r]);
    }
  }
}

extern "C" void kernel_launch(void* const* d_in, const int* in_sizes, int n_in,
                              void* d_out, int out_size, void* d_ws, size_t ws_size,
                              hipStream_t stream) {
  const float* X  = (const float*)d_in[0];   // [2048, 2880]
  // d_in[1] = attention_mask: exactly causal -> handled analytically
  const float* Wq = (const float*)d_in[2];   // [4096, 2880]
  const float* bq = (const float*)d_in[3];
  const float* Wk = (const float*)d_in[4];   // [512, 2880]
  const float* bk = (const float*)d_in[5];
  const float* Wv = (const float*)d_in[6];
  const float* bv = (const float*)d_in[7];
  const float* Wo = (const float*)d_in[8];   // [2880, 4096]
  const float* bo = (const float*)d_in[9];
  float* out = (float*)d_out;                // [2048, 2880] fp32

  char* ws = (char*)d_ws;
  bf16* Qb = (bf16*)(ws);                          // 16 MiB
  bf16* Kb = (bf16*)(ws + 16777216);               // [2048][512]  2 MiB
  bf16* Vt = (bf16*)(ws + 18874368);               // [512][2048]  2 MiB (transposed)
  bf16* AO = (bf16*)(ws + 20971520);               // 16 MiB
  // fast-path extras
  bf16*  Xb   = (bf16*)(ws + 37748736);            // 11.25 MiB
  bf16*  Wall = (bf16*)(ws + 49545216);            // [5120][2880] 29.5 MB (Wq|Wk|Wv)
  bf16*  Wob  = (bf16*)(ws + 79036416);            // 22.5 MiB
  float* ball = (float*)(ws + 102629376);          // 20 KiB
  const size_t NEED = 102649856;

  dim3 blk(256);
  if (ws_size >= NEED) {
    // one-time fp32->bf16 conversion, then all-bf16 async-staged GEMMs
    cvt_f32_bf16<<<dim3(2048 * 2880 / 8 / 256), blk, 0, stream>>>(X, Xb, 2048 * 2880 / 8);
    cvt_f32_bf16<<<dim3(4096 * 2880 / 8 / 256), blk, 0, stream>>>(Wq, Wall, 4096 * 2880 / 8);
    cvt_f32_bf16<<<dim3(512 * 2880 / 8 / 256),  blk, 0, stream>>>(Wk, Wall + (size_t)4096 * 2880, 512 * 2880 / 8);
    cvt_f32_bf16<<<dim3(512 * 2880 / 8 / 256),  blk, 0, stream>>>(Wv, Wall + (size_t)4608 * 2880, 512 * 2880 / 8);
    cvt_f32_bf16<<<dim3(2880 * 4096 / 8 / 256), blk, 0, stream>>>(Wo, Wob, 2880 * 4096 / 8);
    concat_bias3<<<dim3(20), blk, 0, stream>>>(bq, bk, bv, ball);

    // fused QKV projection: N = 4096 + 512 + 512; Q segment pre-scaled
    gemm_bt_bias<1, 1, 4><<<dim3(40, 16), blk, 0, stream>>>(Xb, Wall, ball, Qb, Kb, Vt, 2048, 5120, 2880, QSCALE);
    attn_fused<<<dim3(32, 64), blk, 0, stream>>>(Qb, Kb, Vt, AO);
    gemm_bt_bias<1, 1, 1><<<dim3(23, 16), blk, 0, stream>>>(AO, Wob, bo, out, nullptr, nullptr, 2048, 2880, 4096, 1.f);
  } else {
    // fallback: fp32 staging in-GEMM (round-3 verified path), V written transposed
    gemm_bt_bias<0, 0, 0><<<dim3(32, 16), blk, 0, stream>>>(X, Wq, bq, Qb, nullptr, nullptr, 2048, 4096, 2880, QSCALE);
    gemm_bt_bias<0, 0, 0><<<dim3(4, 16),  blk, 0, stream>>>(X, Wk, bk, Kb, nullptr, nullptr, 2048, 512, 2880, 1.f);
    gemm_bt_bias<0, 0, 2><<<dim3(4, 16),  blk, 0, stream>>>(X, Wv, bv, nullptr, nullptr, Vt, 2048, 512, 2880, 1.f);
    attn_fused<<<dim3(32, 64), blk, 0, stream>>>(Qb, Kb, Vt, AO);
    gemm_bt_bias<1, 0, 1><<<dim3(23, 16), blk, 0, stream>>>(AO, Wo, bo, out, nullptr, nullptr, 2048, 2880, 4096, 1.f);
  }
}

// Round 7
// 599.515 us; speedup vs baseline: 1.1155x; 1.1155x over previous
//
#include <hip/hip_runtime.h>
#include <hip/hip_bf16.h>
#include <cmath>

typedef __hip_bfloat16 bf16;
typedef __bf16 bf16x8 __attribute__((ext_vector_type(8)));
typedef float floatx4 __attribute__((ext_vector_type(4)));

__device__ inline floatx4 mfma16(bf16x8 a, bf16x8 b, floatx4 c) {
  return __builtin_amdgcn_mfma_f32_16x16x32_bf16(a, b, c, 0, 0, 0);
}

// async global->LDS, 16B/lane; lds dest must be wave-uniform (HW adds lane*16)
__device__ inline void async_ld16(const void* g, void* l) {
  __builtin_amdgcn_global_load_lds((const __attribute__((address_space(1))) void*)g,
                                   (__attribute__((address_space(3))) void*)l,
                                   16, 0, 0);
}

// pack 8 fp32 -> 8 bf16 (RNE) -> one 16B store
__device__ inline uint4 pack8(float4 a, float4 b) {
  union { uint4 u; bf16 h[8]; } t;
  t.h[0] = __float2bfloat16(a.x); t.h[1] = __float2bfloat16(a.y);
  t.h[2] = __float2bfloat16(a.z); t.h[3] = __float2bfloat16(a.w);
  t.h[4] = __float2bfloat16(b.x); t.h[5] = __float2bfloat16(b.y);
  t.h[6] = __float2bfloat16(b.z); t.h[7] = __float2bfloat16(b.w);
  return t.u;
}

// bulk fp32 -> bf16 convert, 8 elems/thread
__global__ __launch_bounds__(256)
void cvt_f32_bf16(const float* __restrict__ s, bf16* __restrict__ d, int n8) {
  const int i = blockIdx.x * 256 + threadIdx.x;
  if (i >= n8) return;
  const float4 a = ((const float4*)s)[2 * i];
  const float4 b = ((const float4*)s)[2 * i + 1];
  ((uint4*)d)[i] = pack8(a, b);
}

// ball[5120] = concat(bq[4096], bk[512], bv[512])
__global__ void concat_bias3(const float* __restrict__ q, const float* __restrict__ k,
                             const float* __restrict__ v, float* __restrict__ o) {
  const int i = blockIdx.x * 256 + threadIdx.x;  // 5120 threads
  if (i < 4096) o[i] = q[i];
  else if (i < 4608) o[i] = k[i - 4096];
  else o[i] = v[i - 4608];
}

// Q pre-scale: 1/sqrt(64) * log2(e)  -> softmax runs in exp2 domain
#define QSCALE 0.1803368801111601f

// C = A[M,K] @ B[N,K]^T + bias[N]; bf16 MFMA, fp32 accumulate.
// A_BF/B_BF: operand dtype (bf16 -> global_load_lds path; fp32 -> cvt staging).
// OUT_MODE: 0 = bf16 [M][N] (scaled by qmul); 1 = fp32 [M][N];
//           2 = bf16 transposed Ct[col*M+row];
//           4 = fused QKV route: col<4096 -> Cp (Q, scaled), col<4608 -> Cq (K),
//               else -> Ct (V transposed)
template <int A_BF, int B_BF, int OUT_MODE>
__global__ __launch_bounds__(256)
void gemm_bt_bias(const void* __restrict__ Ap, const void* __restrict__ Bp,
                  const float* __restrict__ bias, void* __restrict__ Cp,
                  void* __restrict__ Cqp, void* __restrict__ Ctp,
                  int M, int N, int K, float qmul) {
  __shared__ __align__(16) bf16 sA[128 * 32];
  __shared__ __align__(16) bf16 sB[128 * 32];
  const int tid  = threadIdx.x;
  const int wave = tid >> 6;
  const int lane = tid & 63;
  const int quad = lane >> 4;
  const int l15  = lane & 15;
  const int bm = blockIdx.y * 128;
  const int bn = blockIdx.x * 128;
  const int wm = (wave & 1) * 64;
  const int wn = (wave >> 1) * 64;

  floatx4 acc[4][4] = {};

  const int g0 = tid, g1 = tid + 256;
  const int arow0 = bm + (g0 >> 2), acol0 = (g0 & 3) * 8;
  const int arow1 = bm + (g1 >> 2), acol1 = (g1 & 3) * 8;
  int brow0 = bn + (g0 >> 2); if (brow0 >= N) brow0 = N - 1;  // N edge: clamp (stores guarded)
  int brow1 = bn + (g1 >> 2); if (brow1 >= N) brow1 = N - 1;

  for (int k0 = 0; k0 < K; k0 += 32) {
    __syncthreads();  // prev iteration's ds_reads done before overwrite
    if (A_BF) {
      const bf16* A = (const bf16*)Ap;
      async_ld16(A + (size_t)arow0 * K + k0 + acol0, sA + wave * 512);
      async_ld16(A + (size_t)arow1 * K + k0 + acol1, sA + 2048 + wave * 512);
    } else {
      const float* A = (const float*)Ap;
      const float* p0 = A + (size_t)arow0 * K + k0 + acol0;
      const float* p1 = A + (size_t)arow1 * K + k0 + acol1;
      *(uint4*)(sA + tid * 8)        = pack8(*(const float4*)p0, *(const float4*)(p0 + 4));
      *(uint4*)(sA + 2048 + tid * 8) = pack8(*(const float4*)p1, *(const float4*)(p1 + 4));
    }
    if (B_BF) {
      const bf16* B = (const bf16*)Bp;
      async_ld16(B + (size_t)brow0 * K + k0 + acol0, sB + wave * 512);
      async_ld16(B + (size_t)brow1 * K + k0 + acol1, sB + 2048 + wave * 512);
    } else {
      const float* B = (const float*)Bp;
      const float* p0 = B + (size_t)brow0 * K + k0 + acol0;
      const float* p1 = B + (size_t)brow1 * K + k0 + acol1;
      *(uint4*)(sB + tid * 8)        = pack8(*(const float4*)p0, *(const float4*)(p0 + 4));
      *(uint4*)(sB + 2048 + tid * 8) = pack8(*(const float4*)p1, *(const float4*)(p1 + 4));
    }
    __syncthreads();  // drains lds-DMA (vmcnt) + ds_writes (lgkmcnt)

    bf16x8 aF[4], bF[4];
#pragma unroll
    for (int mi = 0; mi < 4; ++mi)
      aF[mi] = *(const bf16x8*)(sA + (wm + mi * 16 + l15) * 32 + quad * 8);
#pragma unroll
    for (int ni = 0; ni < 4; ++ni)
      bF[ni] = *(const bf16x8*)(sB + (wn + ni * 16 + l15) * 32 + quad * 8);
#pragma unroll
    for (int mi = 0; mi < 4; ++mi)
#pragma unroll
      for (int ni = 0; ni < 4; ++ni)
        acc[mi][ni] = mfma16(aF[mi], bF[ni], acc[mi][ni]);
  }

  // epilogue: C/D layout col=lane&15, row=quad*4+reg (m89-verified)
#pragma unroll
  for (int ni = 0; ni < 4; ++ni) {
    const int col = bn + wn + ni * 16 + l15;
    if (col >= N) continue;
    const float bv = bias[col];
#pragma unroll
    for (int mi = 0; mi < 4; ++mi) {
      const int row = bm + wm + mi * 16 + quad * 4;
#pragma unroll
      for (int r = 0; r < 4; ++r) {
        const float val = acc[mi][ni][r] + bv;
        if (OUT_MODE == 0) {
          ((bf16*)Cp)[(size_t)(row + r) * N + col] = __float2bfloat16(val * qmul);
        } else if (OUT_MODE == 1) {
          ((float*)Cp)[(size_t)(row + r) * N + col] = val;
        } else if (OUT_MODE == 2) {
          ((bf16*)Ctp)[(size_t)col * M + row + r] = __float2bfloat16(val);
        } else {  // fused QKV routing (segment uniform across the 16-lane store group)
          if (col < 4096)      ((bf16*)Cp)[(size_t)(row + r) * 4096 + col] = __float2bfloat16(val * qmul);
          else if (col < 4608) ((bf16*)Cqp)[(size_t)(row + r) * 512 + (col - 4096)] = __float2bfloat16(val);
          else                 ((bf16*)Ctp)[(size_t)(col - 4608) * M + row + r] = __float2bfloat16(val);
        }
      }
    }
  }
}

// Fused causal GQA attention, flash-style online softmax (exp2 domain; Q pre-scaled).
// grid: (qb, h). 4 waves; each wave owns 16 q-rows.
// K/V staged by DOUBLE-BUFFERED global_load_lds DMA (zero VGPR prefetch state —
// round-5/6 register prefetch spilled: WRITE_SIZE 16->73 MB). One barrier/iter:
// loop-top __syncthreads drains the DMA issued one iteration earlier.
// sK/sV use an XOR-swizzled 16B-granule layout (p = row*8 + (g^(row&7))):
// DMA-compatible (dest = uniform base + lane*16) AND conflict-free b128 reads
// (bank = 4*((ks*4+quad)^(l15&7)) -> 32 banks, 2-way = free). sQ/sP keep pitch 72.
__global__ __launch_bounds__(256)
void attn_fused(const bf16* __restrict__ Q, const bf16* __restrict__ Kc,
                const bf16* __restrict__ Vt, bf16* __restrict__ AO) {
  constexpr int HD = 4096, KD = 512, SEQ = 2048, AP = 72;
  constexpr float NEG = -1e30f;
  __shared__ __align__(16) bf16 sQ[64 * AP];
  __shared__ __align__(16) bf16 sP[64 * AP];
  __shared__ __align__(16) bf16 sK[2][64 * 64];  // [t][d], swizzled granules
  __shared__ __align__(16) bf16 sV[2][64 * 64];  // [d][t], swizzled granules

  const int qb = (int)gridDim.x - 1 - blockIdx.x;  // heavy blocks dispatch first
  const int h  = blockIdx.y;
  const int kvh = h >> 3;        // h // G, G=8
  const int tid = threadIdx.x, wave = tid >> 6, lane = tid & 63;
  const int quad = lane >> 4, l15 = lane & 15;
  const int sq0 = qb * 64;

  // DMA decomposition: chunk c = wave*2+i covers tile rows 8c..8c+7.
  // lane l -> row offset l>>3, logical granule (l&7)^(l>>3); lands at granule c*64+l.
  const int lrow = lane >> 3;
  const int lgr  = (lane & 7) ^ lrow;

  // stage Q tile [64 q][64 d] (pitch 72)
#pragma unroll
  for (int i = 0; i < 2; ++i) {
    const int gidx = tid + i * 256;
    const int r = gidx >> 3, c = (gidx & 7) * 8;
    *(uint4*)(sQ + r * AP + c) = *(const uint4*)(Q + (size_t)(sq0 + r) * HD + h * 64 + c);
  }

  // prologue: DMA tile 0 into buffer 0
#pragma unroll
  for (int i = 0; i < 2; ++i) {
    const int c = wave * 2 + i;
    async_ld16(Kc + (size_t)(c * 8 + lrow) * KD + kvh * 64 + lgr * 8, &sK[0][c * 512]);
    async_ld16(Vt + (size_t)(kvh * 64 + c * 8 + lrow) * SEQ + lgr * 8, &sV[0][c * 512]);
  }

  floatx4 o_acc[4] = {};
  float m_run[4], l_run[4];
#pragma unroll
  for (int r = 0; r < 4; ++r) { m_run[r] = NEG; l_run[r] = 0.f; }

  for (int kt = 0; kt <= qb; ++kt) {   // analytic causality: skip fully-masked key tiles
    const int st0 = kt * 64;
    __syncthreads();  // drains tile-kt DMA (vmcnt) for all waves; protects buffer reuse

    if (kt < qb) {    // issue tile kt+1 DMA; in flight through this compute phase
      const int st1 = st0 + 64;
      const int nb = (kt + 1) & 1;
#pragma unroll
      for (int i = 0; i < 2; ++i) {
        const int c = wave * 2 + i;
        async_ld16(Kc + (size_t)(st1 + c * 8 + lrow) * KD + kvh * 64 + lgr * 8, &sK[nb][c * 512]);
        async_ld16(Vt + (size_t)(kvh * 64 + c * 8 + lrow) * SEQ + st1 + lgr * 8, &sV[nb][c * 512]);
      }
    }
    const bf16* kb = sK[kt & 1];
    const bf16* vb = sV[kt & 1];

    // S = Q K^T : 16 q-rows x 64 t-cols per wave (log2 units)
    floatx4 s_acc[4] = {};
#pragma unroll
    for (int ks = 0; ks < 2; ++ks) {
      const bf16x8 aF = *(const bf16x8*)(sQ + (wave * 16 + l15) * AP + ks * 32 + quad * 8);
#pragma unroll
      for (int ni = 0; ni < 4; ++ni) {
        const bf16x8 bF = *(const bf16x8*)(kb + (ni * 16 + l15) * 64 + (((ks * 4 + quad) ^ (l15 & 7)) * 8));
        s_acc[ni] = mfma16(aF, bF, s_acc[ni]);
      }
    }

    // online softmax (exp2); row = sq0+wave*16+quad*4+r, col = st0+ni*16+l15
    float x[4][4];
    float tmax[4] = {NEG, NEG, NEG, NEG};
    const int qrow = sq0 + wave * 16 + quad * 4;
#pragma unroll
    for (int ni = 0; ni < 4; ++ni) {
      const int tcol = st0 + ni * 16 + l15;
#pragma unroll
      for (int r = 0; r < 4; ++r) {
        float v = s_acc[ni][r];
        if (kt == qb && tcol > qrow + r) v = NEG;
        x[ni][r] = v;
        tmax[r] = fmaxf(tmax[r], v);
      }
    }
#pragma unroll
    for (int off = 1; off < 16; off <<= 1)
#pragma unroll
      for (int r = 0; r < 4; ++r)
        tmax[r] = fmaxf(tmax[r], __shfl_xor(tmax[r], off));

    float alpha[4], rsum[4];
#pragma unroll
    for (int r = 0; r < 4; ++r) {
      const float mn = fmaxf(m_run[r], tmax[r]);
      alpha[r] = exp2f(m_run[r] - mn);
      m_run[r] = mn;
      rsum[r] = 0.f;
    }
#pragma unroll
    for (int ni = 0; ni < 4; ++ni)
#pragma unroll
      for (int r = 0; r < 4; ++r) {
        const float p = exp2f(x[ni][r] - m_run[r]);
        x[ni][r] = p;
        rsum[r] += p;
      }
#pragma unroll
    for (int off = 1; off < 16; off <<= 1)
#pragma unroll
      for (int r = 0; r < 4; ++r)
        rsum[r] += __shfl_xor(rsum[r], off);
#pragma unroll
    for (int r = 0; r < 4; ++r)
      l_run[r] = l_run[r] * alpha[r] + rsum[r];
#pragma unroll
    for (int di = 0; di < 4; ++di)
#pragma unroll
      for (int r = 0; r < 4; ++r)
        o_acc[di][r] *= alpha[r];

    // P: C-layout -> LDS -> A-layout (wave-private rows; in-wave DS ordering)
#pragma unroll
    for (int ni = 0; ni < 4; ++ni)
#pragma unroll
      for (int r = 0; r < 4; ++r)
        sP[(wave * 16 + quad * 4 + r) * AP + ni * 16 + l15] = __float2bfloat16(x[ni][r]);

#pragma unroll
    for (int ks = 0; ks < 2; ++ks) {
      const bf16x8 aF = *(const bf16x8*)(sP + (wave * 16 + l15) * AP + ks * 32 + quad * 8);
#pragma unroll
      for (int di = 0; di < 4; ++di) {
        const bf16x8 bF = *(const bf16x8*)(vb + (di * 16 + l15) * 64 + (((ks * 4 + quad) ^ (l15 & 7)) * 8));
        o_acc[di] = mfma16(aF, bF, o_acc[di]);
      }
    }
  }

  // normalize + store to AO[s][h*64+d]
#pragma unroll
  for (int di = 0; di < 4; ++di) {
    const int col = h * 64 + di * 16 + l15;
#pragma unroll
    for (int r = 0; r < 4; ++r) {
      const int row = sq0 + wave * 16 + quad * 4 + r;
      AO[(size_t)row * HD + col] = __float2bfloat16(o_acc[di][r] / l_run[r]);
    }
  }
}

extern "C" void kernel_launch(void* const* d_in, const int* in_sizes, int n_in,
                              void* d_out, int out_size, void* d_ws, size_t ws_size,
                              hipStream_t stream) {
  const float* X  = (const float*)d_in[0];   // [2048, 2880]
  // d_in[1] = attention_mask: exactly causal -> handled analytically
  const float* Wq = (const float*)d_in[2];   // [4096, 2880]
  const float* bq = (const float*)d_in[3];
  const float* Wk = (const float*)d_in[4];   // [512, 2880]
  const float* bk = (const float*)d_in[5];
  const float* Wv = (const float*)d_in[6];
  const float* bv = (const float*)d_in[7];
  const float* Wo = (const float*)d_in[8];   // [2880, 4096]
  const float* bo = (const float*)d_in[9];
  float* out = (float*)d_out;                // [2048, 2880] fp32

  char* ws = (char*)d_ws;
  bf16* Qb = (bf16*)(ws);                          // 16 MiB
  bf16* Kb = (bf16*)(ws + 16777216);               // [2048][512]  2 MiB
  bf16* Vt = (bf16*)(ws + 18874368);               // [512][2048]  2 MiB (transposed)
  bf16* AO = (bf16*)(ws + 20971520);               // 16 MiB
  // fast-path extras
  bf16*  Xb   = (bf16*)(ws + 37748736);            // 11.25 MiB
  bf16*  Wall = (bf16*)(ws + 49545216);            // [5120][2880] 29.5 MB (Wq|Wk|Wv)
  bf16*  Wob  = (bf16*)(ws + 79036416);            // 22.5 MiB
  float* ball = (float*)(ws + 102629376);          // 20 KiB
  const size_t NEED = 102649856;

  dim3 blk(256);
  if (ws_size >= NEED) {
    // one-time fp32->bf16 conversion, then all-bf16 async-staged GEMMs
    cvt_f32_bf16<<<dim3(2048 * 2880 / 8 / 256), blk, 0, stream>>>(X, Xb, 2048 * 2880 / 8);
    cvt_f32_bf16<<<dim3(4096 * 2880 / 8 / 256), blk, 0, stream>>>(Wq, Wall, 4096 * 2880 / 8);
    cvt_f32_bf16<<<dim3(512 * 2880 / 8 / 256),  blk, 0, stream>>>(Wk, Wall + (size_t)4096 * 2880, 512 * 2880 / 8);
    cvt_f32_bf16<<<dim3(512 * 2880 / 8 / 256),  blk, 0, stream>>>(Wv, Wall + (size_t)4608 * 2880, 512 * 2880 / 8);
    cvt_f32_bf16<<<dim3(2880 * 4096 / 8 / 256), blk, 0, stream>>>(Wo, Wob, 2880 * 4096 / 8);
    concat_bias3<<<dim3(20), blk, 0, stream>>>(bq, bk, bv, ball);

    // fused QKV projection: N = 4096 + 512 + 512; Q segment pre-scaled
    gemm_bt_bias<1, 1, 4><<<dim3(40, 16), blk, 0, stream>>>(Xb, Wall, ball, Qb, Kb, Vt, 2048, 5120, 2880, QSCALE);
    attn_fused<<<dim3(32, 64), blk, 0, stream>>>(Qb, Kb, Vt, AO);
    gemm_bt_bias<1, 1, 1><<<dim3(23, 16), blk, 0, stream>>>(AO, Wob, bo, out, nullptr, nullptr, 2048, 2880, 4096, 1.f);
  } else {
    // fallback: fp32 staging in-GEMM (round-3 verified path), V written transposed
    gemm_bt_bias<0, 0, 0><<<dim3(32, 16), blk, 0, stream>>>(X, Wq, bq, Qb, nullptr, nullptr, 2048, 4096, 2880, QSCALE);
    gemm_bt_bias<0, 0, 0><<<dim3(4, 16),  blk, 0, stream>>>(X, Wk, bk, Kb, nullptr, nullptr, 2048, 512, 2880, 1.f);
    gemm_bt_bias<0, 0, 2><<<dim3(4, 16),  blk, 0, stream>>>(X, Wv, bv, nullptr, nullptr, Vt, 2048, 512, 2880, 1.f);
    attn_fused<<<dim3(32, 64), blk, 0, stream>>>(Qb, Kb, Vt, AO);
    gemm_bt_bias<1, 0, 1><<<dim3(23, 16), blk, 0, stream>>>(AO, Wo, bo, out, nullptr, nullptr, 2048, 2880, 4096, 1.f);
  }
}